// Round 9
// baseline (170.343 us; speedup 1.0000x reference)
//
#include <hip/hip_runtime.h>
#include <hip/hip_bf16.h>

using bf16x8 = __attribute__((ext_vector_type(8))) __bf16;
using f32x4  = __attribute__((ext_vector_type(4))) float;

#define DFEAT 512
#define SLOTS 64

static __device__ __forceinline__ unsigned short f2bfbits(float f) {
    union { float f; unsigned int u; } v; v.f = f;
    unsigned int u = v.u;
    unsigned int r = (u + 0x7fffu + ((u >> 16) & 1u)) >> 16;
    return (unsigned short)r;
}

// -------- fused: fp32->bf16 convert (X,W) + slot-scatter edges by dst --------
__global__ __launch_bounds__(256) void cvt_scatter_kernel(
    const float* __restrict__ x, const float* __restrict__ w,
    unsigned short* __restrict__ Xb, unsigned short* __restrict__ Wb,
    const int* __restrict__ srcv, const int* __restrict__ dstv,
    int* __restrict__ cur, int* __restrict__ slot,
    int nx4, int ntot4, int E, int T)
{
    int i = blockIdx.x * 256 + threadIdx.x;
    if (i < ntot4) {
        const float* in = (i < nx4) ? x : w;
        unsigned short* o = (i < nx4) ? Xb : Wb;
        int j = (i < nx4) ? i : i - nx4;
        float4 v = ((const float4*)in)[j];
        ushort4 u;
        u.x = f2bfbits(v.x); u.y = f2bfbits(v.y);
        u.z = f2bfbits(v.z); u.w = f2bfbits(v.w);
        ((ushort4*)o)[j] = u;
    }
    if (i < T) {
        int s, d;
        if (i < E) { s = srcv[i]; d = dstv[i]; }
        else       { s = d = i - E; }          // self-loops appended
        int pos = atomicAdd(&cur[d], 1);
        if (pos < SLOTS) slot[(size_t)d * SLOTS + pos] = s;
    }
}

// -------- GEMM: H[m][n] = sum_k X[m][k]*W[n][k], bf16 in, bf16 out --------
// Block = 16-row panel x ALL 512 cols (X read exactly once); 4 waves split
// columns: wave w -> cols w*128..w*128+127 (8 MFMA col-groups, acc 32 VGPR).
// W (0.5 MB bf16) is re-read per block but L2-resident per XCD.
// Grid = ceil(N/16) = 625 blocks. 2-stage software pipeline (9 loads + 8 MFMA/k-step).
// A frag: lane holds A[m=lane&15][k=quad*8+j]; B frag: B[k][n=lane&15]=W[n][k]
// C/D: col(n)=lane&15, row(m)=quad*4+reg.
__global__ __launch_bounds__(256) void gemm_h_kernel(
    const unsigned short* __restrict__ X, const unsigned short* __restrict__ Wm,
    const float* __restrict__ avs, const float* __restrict__ avd,
    unsigned short* __restrict__ H, float* __restrict__ es, float* __restrict__ ed,
    int N)
{
    int bm   = blockIdx.x * 16;
    int wave = threadIdx.x >> 6;
    int lane = threadIdx.x & 63;
    int l15  = lane & 15;
    int quad = lane >> 4;
    int bn   = wave * 128;

    int rowA = bm + l15;
    int ra   = rowA < N ? rowA : N - 1;      // clamp: garbage rows never stored

    const bf16x8* A = (const bf16x8*)(X + (size_t)ra * DFEAT);
    const bf16x8* Bp[8];
    #pragma unroll
    for (int nt = 0; nt < 8; ++nt)
        Bp[nt] = (const bf16x8*)(Wm + (size_t)(bn + nt * 16 + l15) * DFEAT);

    f32x4 acc[8] = {};

    // 2-stage pipeline over 16 k-steps (K=512, 32 per MFMA)
    int kidx = quad;
    bf16x8 a = A[kidx];
    bf16x8 b[8];
    #pragma unroll
    for (int nt = 0; nt < 8; ++nt) b[nt] = Bp[nt][kidx];

    for (int k0 = 1; k0 <= 16; ++k0) {
        int kn = ((k0 < 16 ? k0 : 15) * 4) + quad;
        bf16x8 a_n = A[kn];
        bf16x8 b_n[8];
        #pragma unroll
        for (int nt = 0; nt < 8; ++nt) b_n[nt] = Bp[nt][kn];
        #pragma unroll
        for (int nt = 0; nt < 8; ++nt)
            acc[nt] = __builtin_amdgcn_mfma_f32_16x16x32_bf16(a, b[nt], acc[nt], 0, 0, 0);
        a = a_n;
        #pragma unroll
        for (int nt = 0; nt < 8; ++nt) b[nt] = b_n[nt];
    }

    float as[8], ad[8];
    #pragma unroll
    for (int nt = 0; nt < 8; ++nt) {
        as[nt] = avs[bn + nt * 16 + l15];
        ad[nt] = avd[bn + nt * 16 + l15];
    }

    int rbase = bm + quad * 4;
    #pragma unroll
    for (int nt = 0; nt < 8; ++nt) {
        int col = bn + nt * 16 + l15;
        #pragma unroll
        for (int r = 0; r < 4; ++r) {
            int row = rbase + r;
            if (row < N) H[(size_t)row * DFEAT + col] = f2bfbits(acc[nt][r]);
        }
    }
    #pragma unroll
    for (int r = 0; r < 4; ++r) {
        float ps = 0.f, pd = 0.f;
        #pragma unroll
        for (int nt = 0; nt < 8; ++nt) {
            ps += acc[nt][r] * as[nt];
            pd += acc[nt][r] * ad[nt];
        }
        #pragma unroll
        for (int m = 1; m < 16; m <<= 1) {
            ps += __shfl_xor(ps, m);
            pd += __shfl_xor(pd, m);
        }
        int row = rbase + r;
        if (l15 == 0 && row < N) {
            atomicAdd(&es[row], ps);
            atomicAdd(&ed[row], pd);
        }
    }
}

// -------- aggregate: one WAVE per node; lane j owns slot j; 16B/lane row reads --------
__global__ __launch_bounds__(256) void aggregate_kernel(
    const unsigned short* __restrict__ H, const float* __restrict__ x,
    const float* __restrict__ bias,
    const int* __restrict__ cur, const int* __restrict__ slot,
    const float* __restrict__ es, const float* __restrict__ ed,
    float* __restrict__ out, int N)
{
    int node = (blockIdx.x * 256 + threadIdx.x) >> 6;
    int lane = threadIdx.x & 63;
    if (node >= N) return;

    int k = cur[node];
    if (k > SLOTS) k = SLOTS;

    int   s = 0;
    float w = 0.f;
    if (lane < k) {
        s = slot[(size_t)node * SLOTS + lane];
        float e = es[s] + ed[node];
        e = e > 0.f ? e : 0.2f * e;            // leaky_relu
        w = __expf(e);                          // |e| small: no max-subtraction needed
    }
    float denom = w;
    #pragma unroll
    for (int off = 32; off > 0; off >>= 1) denom += __shfl_xor(denom, off);
    float inv = 1.0f / denom;

    float a[8] = {};
    const unsigned short* Hl = H + lane * 8;   // this lane's 8 features (16 B)

    auto accum = [&](int sj, float wj) {
        uint4 hv = *(const uint4*)(Hl + (size_t)sj * DFEAT);
        a[0] += wj * __uint_as_float(hv.x << 16);
        a[1] += wj * __uint_as_float(hv.x & 0xffff0000u);
        a[2] += wj * __uint_as_float(hv.y << 16);
        a[3] += wj * __uint_as_float(hv.y & 0xffff0000u);
        a[4] += wj * __uint_as_float(hv.z << 16);
        a[5] += wj * __uint_as_float(hv.z & 0xffff0000u);
        a[6] += wj * __uint_as_float(hv.w << 16);
        a[7] += wj * __uint_as_float(hv.w & 0xffff0000u);
    };

    int j = 0;
    for (; j + 3 < k; j += 4) {                // 4 row-gathers in flight
        int   s0 = __shfl(s, j),     s1 = __shfl(s, j + 1);
        int   s2 = __shfl(s, j + 2), s3 = __shfl(s, j + 3);
        float w0 = __shfl(w, j),     w1 = __shfl(w, j + 1);
        float w2 = __shfl(w, j + 2), w3 = __shfl(w, j + 3);
        uint4 h0 = *(const uint4*)(Hl + (size_t)s0 * DFEAT);
        uint4 h1 = *(const uint4*)(Hl + (size_t)s1 * DFEAT);
        uint4 h2 = *(const uint4*)(Hl + (size_t)s2 * DFEAT);
        uint4 h3 = *(const uint4*)(Hl + (size_t)s3 * DFEAT);
        a[0] += w0 * __uint_as_float(h0.x << 16);
        a[1] += w0 * __uint_as_float(h0.x & 0xffff0000u);
        a[2] += w0 * __uint_as_float(h0.y << 16);
        a[3] += w0 * __uint_as_float(h0.y & 0xffff0000u);
        a[4] += w0 * __uint_as_float(h0.z << 16);
        a[5] += w0 * __uint_as_float(h0.z & 0xffff0000u);
        a[6] += w0 * __uint_as_float(h0.w << 16);
        a[7] += w0 * __uint_as_float(h0.w & 0xffff0000u);
        a[0] += w1 * __uint_as_float(h1.x << 16);
        a[1] += w1 * __uint_as_float(h1.x & 0xffff0000u);
        a[2] += w1 * __uint_as_float(h1.y << 16);
        a[3] += w1 * __uint_as_float(h1.y & 0xffff0000u);
        a[4] += w1 * __uint_as_float(h1.z << 16);
        a[5] += w1 * __uint_as_float(h1.z & 0xffff0000u);
        a[6] += w1 * __uint_as_float(h1.w << 16);
        a[7] += w1 * __uint_as_float(h1.w & 0xffff0000u);
        a[0] += w2 * __uint_as_float(h2.x << 16);
        a[1] += w2 * __uint_as_float(h2.x & 0xffff0000u);
        a[2] += w2 * __uint_as_float(h2.y << 16);
        a[3] += w2 * __uint_as_float(h2.y & 0xffff0000u);
        a[4] += w2 * __uint_as_float(h2.z << 16);
        a[5] += w2 * __uint_as_float(h2.z & 0xffff0000u);
        a[6] += w2 * __uint_as_float(h2.w << 16);
        a[7] += w2 * __uint_as_float(h2.w & 0xffff0000u);
        a[0] += w3 * __uint_as_float(h3.x << 16);
        a[1] += w3 * __uint_as_float(h3.x & 0xffff0000u);
        a[2] += w3 * __uint_as_float(h3.y << 16);
        a[3] += w3 * __uint_as_float(h3.y & 0xffff0000u);
        a[4] += w3 * __uint_as_float(h3.z << 16);
        a[5] += w3 * __uint_as_float(h3.z & 0xffff0000u);
        a[6] += w3 * __uint_as_float(h3.w << 16);
        a[7] += w3 * __uint_as_float(h3.w & 0xffff0000u);
    }
    for (; j < k; ++j) accum(__shfl(s, j), __shfl(w, j));

    int c = lane * 8;
    float4 b0 = *(const float4*)(bias + c);
    float4 b1 = *(const float4*)(bias + c + 4);
    float4 x0 = *(const float4*)(x + (size_t)node * DFEAT + c);
    float4 x1 = *(const float4*)(x + (size_t)node * DFEAT + c + 4);
    float r[8];
    r[0] = a[0] * inv + b0.x; r[1] = a[1] * inv + b0.y;
    r[2] = a[2] * inv + b0.z; r[3] = a[3] * inv + b0.w;
    r[4] = a[4] * inv + b1.x; r[5] = a[5] * inv + b1.y;
    r[6] = a[6] * inv + b1.z; r[7] = a[7] * inv + b1.w;
    #pragma unroll
    for (int i = 0; i < 8; ++i)
        r[i] = r[i] > 0.f ? r[i] : __expf(r[i]) - 1.f;   // elu
    float4 o0 = make_float4(x0.x + r[0], x0.y + r[1], x0.z + r[2], x0.w + r[3]);
    float4 o1 = make_float4(x1.x + r[4], x1.y + r[5], x1.z + r[6], x1.w + r[7]);
    *(float4*)(out + (size_t)node * DFEAT + c)     = o0;
    *(float4*)(out + (size_t)node * DFEAT + c + 4) = o1;
}

extern "C" void kernel_launch(void* const* d_in, const int* in_sizes, int n_in,
                              void* d_out, int out_size, void* d_ws, size_t ws_size,
                              hipStream_t stream)
{
    const float* x    = (const float*)d_in[0];
    const int*   edge = (const int*)d_in[1];
    const float* Wm   = (const float*)d_in[2];
    const float* avs  = (const float*)d_in[3];
    const float* avd  = (const float*)d_in[4];
    const float* bias = (const float*)d_in[5];

    const int D = DFEAT;
    const int N = in_sizes[0] / D;
    const int E = in_sizes[1] / 2;
    const int T = E + N;
    const int* srcv = edge;
    const int* dstv = edge + E;

    char* ws = (char*)d_ws;
    size_t off = 0;
    auto alloc = [&](size_t bytes) -> char* {
        char* p = ws + off;
        off += (bytes + 255) & ~(size_t)255;
        return p;
    };
    // zero region: cur[N] | es[N] | ed[N]
    int*   cur  = (int*)alloc((size_t)N * 3 * 4);
    float* es   = (float*)(cur + N);
    float* ed   = es + N;
    int*   slot = (int*)alloc((size_t)N * SLOTS * 4);
    unsigned short* Xb = (unsigned short*)alloc((size_t)N * D * 2);
    unsigned short* Wb = (unsigned short*)alloc((size_t)D * D * 2);
    unsigned short* H  = (unsigned short*)alloc((size_t)N * D * 2);

    hipMemsetAsync(cur, 0, (size_t)N * 3 * 4, stream);

    int nx4   = (N * D) / 4;
    int ntot4 = nx4 + (D * D) / 4;
    int grid0 = (ntot4 > T ? ntot4 : T);
    cvt_scatter_kernel<<<dim3((grid0 + 255) / 256), 256, 0, stream>>>(
        x, Wm, Xb, Wb, srcv, dstv, cur, slot, nx4, ntot4, E, T);

    gemm_h_kernel<<<dim3((N + 15) / 16), 256, 0, stream>>>(
        Xb, Wb, avs, avd, H, es, ed, N);
    aggregate_kernel<<<dim3((N * 64 + 255) / 256), 256, 0, stream>>>(
        H, x, bias, cur, slot, es, ed, (float*)d_out, N);
}

// Round 11
// 144.161 us; speedup vs baseline: 1.1816x; 1.1816x over previous
//
#include <hip/hip_runtime.h>
#include <hip/hip_bf16.h>

using bf16x8 = __attribute__((ext_vector_type(8))) __bf16;
using f32x4  = __attribute__((ext_vector_type(4))) float;

#define DFEAT 512
#define SLOTS 64

static __device__ __forceinline__ unsigned short f2bfbits(float f) {
    union { float f; unsigned int u; } v; v.f = f;
    unsigned int u = v.u;
    unsigned int r = (u + 0x7fffu + ((u >> 16) & 1u)) >> 16;
    return (unsigned short)r;
}

// -------- fused: fp32->bf16 convert (X,W) + slot-scatter edges by dst --------
__global__ __launch_bounds__(256) void cvt_scatter_kernel(
    const float* __restrict__ x, const float* __restrict__ w,
    unsigned short* __restrict__ Xb, unsigned short* __restrict__ Wb,
    const int* __restrict__ srcv, const int* __restrict__ dstv,
    int* __restrict__ cur, int* __restrict__ slot,
    int nx4, int ntot4, int E, int T)
{
    int i = blockIdx.x * 256 + threadIdx.x;
    if (i < ntot4) {
        const float* in = (i < nx4) ? x : w;
        unsigned short* o = (i < nx4) ? Xb : Wb;
        int j = (i < nx4) ? i : i - nx4;
        float4 v = ((const float4*)in)[j];
        ushort4 u;
        u.x = f2bfbits(v.x); u.y = f2bfbits(v.y);
        u.z = f2bfbits(v.z); u.w = f2bfbits(v.w);
        ((ushort4*)o)[j] = u;
    }
    if (i < T) {
        int s, d;
        if (i < E) { s = srcv[i]; d = dstv[i]; }
        else       { s = d = i - E; }          // self-loops appended
        int pos = atomicAdd(&cur[d], 1);
        if (pos < SLOTS) slot[(size_t)d * SLOTS + pos] = s;
    }
}

// -------- GEMM: H[m][n] = sum_k X[m][k]*W[n][k], bf16, LDS-staged W panel --------
// Block = 128 rows x 64 cols. W panel (64 rows x K=512 = 64 KiB) staged to LDS with
// XOR chunk swizzle (chunk' = chunk ^ (row&7)) -> 2-way bank aliasing only (free).
// K-loop: B-frags from LDS (1-step prefetch, ds_read_b128) + A-frags from global
// (2-step register prefetch) + 8 MFMA/step. 4 waves: wave w -> rows bm+w*32..+31.
// XCD swizzle: 8 col-panels of a row-panel land on one XCD -> X re-reads are L2 hits.
// A frag: lane holds A[m=lane&15][k=quad*8+j]; B frag: B[k][n=lane&15]=W[n][k]
// C/D: col(n)=lane&15, row(m)=quad*4+reg.
__global__ __launch_bounds__(256, 2) void gemm_h_kernel(
    const unsigned short* __restrict__ X, const unsigned short* __restrict__ Wm,
    const float* __restrict__ avs, const float* __restrict__ avd,
    unsigned short* __restrict__ H, float* __restrict__ es, float* __restrict__ ed,
    int N)
{
    __shared__ unsigned short Bl[64 * 512];    // exactly 64 KiB

    int L = blockIdx.x;
    int xcd = L & 7;
    int j   = L >> 3;
    int rpan = (j >> 3) * 8 + xcd;             // row panel
    int cpan = j & 7;                          // col panel
    int rowPanels = (N + 127) >> 7;
    if (rpan >= rowPanels) return;
    int bm = rpan * 128;
    int bn = cpan * 64;

    int tid  = threadIdx.x;
    int wave = tid >> 6;
    int lane = tid & 63;
    int l15  = lane & 15;
    int quad = lane >> 4;

    // ---- stage W[bn..bn+63][0..511] into LDS, full rows, XOR-swizzled chunks ----
    for (int idx = tid; idx < 64 * 64; idx += 256) {
        int n = idx >> 6, c = idx & 63;        // c: 16B chunk within row (64 chunks)
        uint4 v = *(const uint4*)(Wm + (size_t)(bn + n) * DFEAT + c * 8);
        int cs = c ^ (n & 7);
        *(uint4*)((char*)Bl + (size_t)n * 1024 + cs * 16) = v;
    }
    __syncthreads();

    int r0 = bm + wave * 32 + l15;
    int r1 = r0 + 16;
    int ra0 = r0 < N ? r0 : N - 1;             // clamp: garbage rows never stored
    int ra1 = r1 < N ? r1 : N - 1;
    const bf16x8* A0 = (const bf16x8*)(X + (size_t)ra0 * DFEAT);
    const bf16x8* A1 = (const bf16x8*)(X + (size_t)ra1 * DFEAT);
    const char* Bc = (const char*)Bl;
    int xorm = l15 & 7;                        // row&7 for this lane's B rows
    int roff0 = (0 * 16 + l15) * 1024;
    int roff1 = (1 * 16 + l15) * 1024;
    int roff2 = (2 * 16 + l15) * 1024;
    int roff3 = (3 * 16 + l15) * 1024;

    f32x4 acc[2][4] = {};

    // pipeline: A 2-step prefetch (global), B 1-step prefetch (LDS)
    bf16x8 a0c = A0[quad],     a1c = A1[quad];
    bf16x8 a0n = A0[4 + quad], a1n = A1[4 + quad];
    bf16x8 b[4];
    {
        int cb = ((quad ^ xorm) * 16);
        b[0] = *(const bf16x8*)(Bc + roff0 + cb);
        b[1] = *(const bf16x8*)(Bc + roff1 + cb);
        b[2] = *(const bf16x8*)(Bc + roff2 + cb);
        b[3] = *(const bf16x8*)(Bc + roff3 + cb);
    }

    for (int k0 = 0; k0 < 16; ++k0) {
        int ka = ((k0 + 2 < 16 ? k0 + 2 : 15) * 4) + quad;
        bf16x8 a0f = A0[ka];
        bf16x8 a1f = A1[ka];
        int kb = ((k0 + 1 < 16 ? k0 + 1 : 15) * 4) + quad;
        int cb = (kb ^ xorm) * 16;
        bf16x8 bn0 = *(const bf16x8*)(Bc + roff0 + cb);
        bf16x8 bn1 = *(const bf16x8*)(Bc + roff1 + cb);
        bf16x8 bn2 = *(const bf16x8*)(Bc + roff2 + cb);
        bf16x8 bn3 = *(const bf16x8*)(Bc + roff3 + cb);
        acc[0][0] = __builtin_amdgcn_mfma_f32_16x16x32_bf16(a0c, b[0], acc[0][0], 0, 0, 0);
        acc[1][0] = __builtin_amdgcn_mfma_f32_16x16x32_bf16(a1c, b[0], acc[1][0], 0, 0, 0);
        acc[0][1] = __builtin_amdgcn_mfma_f32_16x16x32_bf16(a0c, b[1], acc[0][1], 0, 0, 0);
        acc[1][1] = __builtin_amdgcn_mfma_f32_16x16x32_bf16(a1c, b[1], acc[1][1], 0, 0, 0);
        acc[0][2] = __builtin_amdgcn_mfma_f32_16x16x32_bf16(a0c, b[2], acc[0][2], 0, 0, 0);
        acc[1][2] = __builtin_amdgcn_mfma_f32_16x16x32_bf16(a1c, b[2], acc[1][2], 0, 0, 0);
        acc[0][3] = __builtin_amdgcn_mfma_f32_16x16x32_bf16(a0c, b[3], acc[0][3], 0, 0, 0);
        acc[1][3] = __builtin_amdgcn_mfma_f32_16x16x32_bf16(a1c, b[3], acc[1][3], 0, 0, 0);
        a0c = a0n; a1c = a1n; a0n = a0f; a1n = a1f;
        b[0] = bn0; b[1] = bn1; b[2] = bn2; b[3] = bn3;
    }

    float as[4], ad[4];
    #pragma unroll
    for (int nt = 0; nt < 4; ++nt) {
        as[nt] = avs[bn + nt * 16 + l15];
        ad[nt] = avd[bn + nt * 16 + l15];
    }

    #pragma unroll
    for (int mt = 0; mt < 2; ++mt) {
        int rbase = bm + wave * 32 + mt * 16 + quad * 4;
        #pragma unroll
        for (int nt = 0; nt < 4; ++nt) {
            int col = bn + nt * 16 + l15;
            #pragma unroll
            for (int r = 0; r < 4; ++r) {
                int row = rbase + r;
                if (row < N) H[(size_t)row * DFEAT + col] = f2bfbits(acc[mt][nt][r]);
            }
        }
        #pragma unroll
        for (int r = 0; r < 4; ++r) {
            float ps = acc[mt][0][r] * as[0] + acc[mt][1][r] * as[1]
                     + acc[mt][2][r] * as[2] + acc[mt][3][r] * as[3];
            float pd = acc[mt][0][r] * ad[0] + acc[mt][1][r] * ad[1]
                     + acc[mt][2][r] * ad[2] + acc[mt][3][r] * ad[3];
            #pragma unroll
            for (int m = 1; m < 16; m <<= 1) {
                ps += __shfl_xor(ps, m);
                pd += __shfl_xor(pd, m);
            }
            int row = rbase + r;
            if (l15 == 0 && row < N) {
                atomicAdd(&es[row], ps);
                atomicAdd(&ed[row], pd);
            }
        }
    }
}

// -------- aggregate: one WAVE per node; lane j owns slot j; 16B/lane row reads --------
__global__ __launch_bounds__(256) void aggregate_kernel(
    const unsigned short* __restrict__ H, const float* __restrict__ x,
    const float* __restrict__ bias,
    const int* __restrict__ cur, const int* __restrict__ slot,
    const float* __restrict__ es, const float* __restrict__ ed,
    float* __restrict__ out, int N)
{
    int node = (blockIdx.x * 256 + threadIdx.x) >> 6;
    int lane = threadIdx.x & 63;
    if (node >= N) return;

    int k = cur[node];
    if (k > SLOTS) k = SLOTS;

    int   s = 0;
    float w = 0.f;
    if (lane < k) {
        s = slot[(size_t)node * SLOTS + lane];
        float e = es[s] + ed[node];
        e = e > 0.f ? e : 0.2f * e;            // leaky_relu
        w = __expf(e);                          // |e| small: no max-subtraction needed
    }
    float denom = w;
    #pragma unroll
    for (int off = 32; off > 0; off >>= 1) denom += __shfl_xor(denom, off);
    float inv = 1.0f / denom;

    float a[8] = {};
    const unsigned short* Hl = H + lane * 8;   // this lane's 8 features (16 B)

    auto accum = [&](int sj, float wj) {
        uint4 hv = *(const uint4*)(Hl + (size_t)sj * DFEAT);
        a[0] += wj * __uint_as_float(hv.x << 16);
        a[1] += wj * __uint_as_float(hv.x & 0xffff0000u);
        a[2] += wj * __uint_as_float(hv.y << 16);
        a[3] += wj * __uint_as_float(hv.y & 0xffff0000u);
        a[4] += wj * __uint_as_float(hv.z << 16);
        a[5] += wj * __uint_as_float(hv.z & 0xffff0000u);
        a[6] += wj * __uint_as_float(hv.w << 16);
        a[7] += wj * __uint_as_float(hv.w & 0xffff0000u);
    };

    int j = 0;
    for (; j + 3 < k; j += 4) {                // 4 row-gathers in flight
        int   s0 = __shfl(s, j),     s1 = __shfl(s, j + 1);
        int   s2 = __shfl(s, j + 2), s3 = __shfl(s, j + 3);
        float w0 = __shfl(w, j),     w1 = __shfl(w, j + 1);
        float w2 = __shfl(w, j + 2), w3 = __shfl(w, j + 3);
        uint4 h0 = *(const uint4*)(Hl + (size_t)s0 * DFEAT);
        uint4 h1 = *(const uint4*)(Hl + (size_t)s1 * DFEAT);
        uint4 h2 = *(const uint4*)(Hl + (size_t)s2 * DFEAT);
        uint4 h3 = *(const uint4*)(Hl + (size_t)s3 * DFEAT);
        a[0] += w0 * __uint_as_float(h0.x << 16);
        a[1] += w0 * __uint_as_float(h0.x & 0xffff0000u);
        a[2] += w0 * __uint_as_float(h0.y << 16);
        a[3] += w0 * __uint_as_float(h0.y & 0xffff0000u);
        a[4] += w0 * __uint_as_float(h0.z << 16);
        a[5] += w0 * __uint_as_float(h0.z & 0xffff0000u);
        a[6] += w0 * __uint_as_float(h0.w << 16);
        a[7] += w0 * __uint_as_float(h0.w & 0xffff0000u);
        a[0] += w1 * __uint_as_float(h1.x << 16);
        a[1] += w1 * __uint_as_float(h1.x & 0xffff0000u);
        a[2] += w1 * __uint_as_float(h1.y << 16);
        a[3] += w1 * __uint_as_float(h1.y & 0xffff0000u);
        a[4] += w1 * __uint_as_float(h1.z << 16);
        a[5] += w1 * __uint_as_float(h1.z & 0xffff0000u);
        a[6] += w1 * __uint_as_float(h1.w << 16);
        a[7] += w1 * __uint_as_float(h1.w & 0xffff0000u);
        a[0] += w2 * __uint_as_float(h2.x << 16);
        a[1] += w2 * __uint_as_float(h2.x & 0xffff0000u);
        a[2] += w2 * __uint_as_float(h2.y << 16);
        a[3] += w2 * __uint_as_float(h2.y & 0xffff0000u);
        a[4] += w2 * __uint_as_float(h2.z << 16);
        a[5] += w2 * __uint_as_float(h2.z & 0xffff0000u);
        a[6] += w2 * __uint_as_float(h2.w << 16);
        a[7] += w2 * __uint_as_float(h2.w & 0xffff0000u);
        a[0] += w3 * __uint_as_float(h3.x << 16);
        a[1] += w3 * __uint_as_float(h3.x & 0xffff0000u);
        a[2] += w3 * __uint_as_float(h3.y << 16);
        a[3] += w3 * __uint_as_float(h3.y & 0xffff0000u);
        a[4] += w3 * __uint_as_float(h3.z << 16);
        a[5] += w3 * __uint_as_float(h3.z & 0xffff0000u);
        a[6] += w3 * __uint_as_float(h3.w << 16);
        a[7] += w3 * __uint_as_float(h3.w & 0xffff0000u);
    }
    for (; j < k; ++j) accum(__shfl(s, j), __shfl(w, j));

    int c = lane * 8;
    float4 b0 = *(const float4*)(bias + c);
    float4 b1 = *(const float4*)(bias + c + 4);
    float4 x0 = *(const float4*)(x + (size_t)node * DFEAT + c);
    float4 x1 = *(const float4*)(x + (size_t)node * DFEAT + c + 4);
    float r[8];
    r[0] = a[0] * inv + b0.x; r[1] = a[1] * inv + b0.y;
    r[2] = a[2] * inv + b0.z; r[3] = a[3] * inv + b0.w;
    r[4] = a[4] * inv + b1.x; r[5] = a[5] * inv + b1.y;
    r[6] = a[6] * inv + b1.z; r[7] = a[7] * inv + b1.w;
    #pragma unroll
    for (int i = 0; i < 8; ++i)
        r[i] = r[i] > 0.f ? r[i] : __expf(r[i]) - 1.f;   // elu
    float4 o0 = make_float4(x0.x + r[0], x0.y + r[1], x0.z + r[2], x0.w + r[3]);
    float4 o1 = make_float4(x1.x + r[4], x1.y + r[5], x1.z + r[6], x1.w + r[7]);
    *(float4*)(out + (size_t)node * DFEAT + c)     = o0;
    *(float4*)(out + (size_t)node * DFEAT + c + 4) = o1;
}

extern "C" void kernel_launch(void* const* d_in, const int* in_sizes, int n_in,
                              void* d_out, int out_size, void* d_ws, size_t ws_size,
                              hipStream_t stream)
{
    const float* x    = (const float*)d_in[0];
    const int*   edge = (const int*)d_in[1];
    const float* Wm   = (const float*)d_in[2];
    const float* avs  = (const float*)d_in[3];
    const float* avd  = (const float*)d_in[4];
    const float* bias = (const float*)d_in[5];

    const int D = DFEAT;
    const int N = in_sizes[0] / D;
    const int E = in_sizes[1] / 2;
    const int T = E + N;
    const int* srcv = edge;
    const int* dstv = edge + E;

    char* ws = (char*)d_ws;
    size_t off = 0;
    auto alloc = [&](size_t bytes) -> char* {
        char* p = ws + off;
        off += (bytes + 255) & ~(size_t)255;
        return p;
    };
    // zero region: cur[N] | es[N] | ed[N]
    int*   cur  = (int*)alloc((size_t)N * 3 * 4);
    float* es   = (float*)(cur + N);
    float* ed   = es + N;
    int*   slot = (int*)alloc((size_t)N * SLOTS * 4);
    unsigned short* Xb = (unsigned short*)alloc((size_t)N * D * 2);
    unsigned short* Wb = (unsigned short*)alloc((size_t)D * D * 2);
    unsigned short* H  = (unsigned short*)alloc((size_t)N * D * 2);

    hipMemsetAsync(cur, 0, (size_t)N * 3 * 4, stream);

    int nx4   = (N * D) / 4;
    int ntot4 = nx4 + (D * D) / 4;
    int grid0 = (ntot4 > T ? ntot4 : T);
    cvt_scatter_kernel<<<dim3((grid0 + 255) / 256), 256, 0, stream>>>(
        x, Wm, Xb, Wb, srcv, dstv, cur, slot, nx4, ntot4, E, T);

    int rowPanels  = (N + 127) / 128;
    int rowPanels8 = ((rowPanels + 7) / 8) * 8;
    gemm_h_kernel<<<dim3(rowPanels8 * 8), 256, 0, stream>>>(
        Xb, Wb, avs, avd, H, es, ed, N);
    aggregate_kernel<<<dim3((N * 64 + 255) / 256), 256, 0, stream>>>(
        H, x, bias, cur, slot, es, ed, (float*)d_out, N);
}